// Round 1
// baseline (233.991 us; speedup 1.0000x reference)
//
#include <hip/hip_runtime.h>
#include <hip/hip_bf16.h>

#define BN    4
#define NN    2048
#define INF   128
#define HH    8
#define HD    16
#define ALPHA 0.2f
#define DECAY 0.1f

// exp2 folding constants: w2 = log2e * exp(-DECAY*(ct - t)) computed as
// exp2(fma(DECAY*log2e, t, -DECAY*log2e*ct + log2(log2e)))
#define DLOG2E 0.14426950408889634f   // DECAY * log2(e)
#define LLOG2E 0.5287663729448977f    // log2(log2(e))
#define MBIAS  -30000.0f              // masked bias: exp2(-30000+|sc*w2|) == 0

typedef __attribute__((ext_vector_type(8))) short short8;
typedef __attribute__((ext_vector_type(4))) float float4v;

__device__ __forceinline__ float bf2f(unsigned short u) {
    return __uint_as_float(((unsigned)u) << 16);
}

// ---------------- Kernel 1: fused [max over tm] + [proj h_t/es/ed] ---------
// blocks 0..1023: grid-stride max reduction (HBM-bound).
// blocks 1024..5119: projection, 2 nodes per block (latency-bound; overlaps).
__launch_bounds__(256, 8)
__global__ void k_setup(const float* __restrict__ x,
                        const float* __restrict__ W,
                        const float* __restrict__ a,
                        const float* __restrict__ tm,
                        unsigned* __restrict__ ct,
                        __hip_bfloat16* __restrict__ h_t,
                        float* __restrict__ es, float* __restrict__ ed) {
    if (blockIdx.x < 1024) {
        // ---- role A: ct = max(tm), values >= 0 so u32-compare == f32-compare
        const uint4* p = (const uint4*)tm;
        const int nvec = BN * NN * NN / 4;  // 4,194,304
        int idx = blockIdx.x * 256 + threadIdx.x;
        const int stride = 1024 * 256;
        unsigned m = 0u;
        for (int i = idx; i < nvec; i += stride) {
            uint4 v = p[i];
            m = max(m, v.x); m = max(m, v.y); m = max(m, v.z); m = max(m, v.w);
        }
        float fm = __uint_as_float(m);
        #pragma unroll
        for (int o = 32; o >= 1; o >>= 1) fm = fmaxf(fm, __shfl_xor(fm, o));
        __shared__ float sm[4];
        if ((threadIdx.x & 63) == 0) sm[threadIdx.x >> 6] = fm;
        __syncthreads();
        if (threadIdx.x == 0) {
            float mm = fmaxf(fmaxf(sm[0], sm[1]), fmaxf(sm[2], sm[3]));
            atomicMax(ct, __float_as_uint(mm));
        }
    } else {
        // ---- role B: h = x W ; h_t (bf16 transposed) ; es ; ed
        int bid = blockIdx.x - 1024;          // 0..4095
        int sub = threadIdx.x >> 7;           // which of 2 nodes
        int tt  = threadIdx.x & 127;
        int nn  = bid * 2 + sub;              // global node 0..8191 (= b*NN+n)
        __shared__ float xs[2][INF];
        xs[sub][tt] = x[(size_t)nn * INF + tt];
        __syncthreads();
        int h = tt >> 4, d = tt & 15;
        const float* Wp = W + (h * INF) * HD + d;
        float acc = 0.f;
        #pragma unroll 16
        for (int i = 0; i < INF; i++) acc += xs[sub][i] * Wp[i * HD];
        int b = nn >> 11, n = nn & 2047;
        h_t[((size_t)((b * HH + h) * HD + d)) * NN + n] = __float2bfloat16(acc);
        float s  = acc * a[h * 2 * HD + d];
        float dd = acc * a[h * 2 * HD + HD + d];
        #pragma unroll
        for (int o = 8; o >= 1; o >>= 1) { s += __shfl_xor(s, o); dd += __shfl_xor(dd, o); }
        if (d == 0) {
            es[(b * HH + h) * NN + n] = s;
            ed[(b * HH + h) * NN + n] = dd;
        }
    }
}

// ---------------- Kernel 2: fused scores + softmax + PV + ELU (full row) ---
// grid: B * 128 i-tiles = 512 blocks -> 2 blocks/CU (LDS 66KB, VGPR<=128).
// block: 512 thr = 8 waves, wave = head. Per 128-j round the block stages the
// head-independent (w2, mask-bias) planes into double-buffered LDS. Masking is
// folded into the staged bias: pv = exp2(fma(sc, w2, m)) with m in {0,-30000},
// so the inner loop has no cmp/cndmask. Full j per block -> finalize softmax
// normalization + ELU + store out directly (no partials, no k_fin).
__launch_bounds__(512, 4)
__global__ void k_attn(const int* __restrict__ adj,
                       const float* __restrict__ tm,
                       const __hip_bfloat16* __restrict__ h_t,
                       const float* __restrict__ es, const float* __restrict__ ed,
                       const unsigned* __restrict__ ctp,
                       float* __restrict__ out) {
    int t    = threadIdx.x;
    int w    = t >> 6;          // head
    int lane = t & 63;
    int q    = lane >> 4;       // quad 0..3
    int im   = lane & 15;       // i within tile / d for B-frag
    int bx   = blockIdx.x;
    int b    = bx >> 7;
    int i0   = (bx & 127) << 4;
    int i    = i0 + im;
    const int R = 16;           // 16 rounds x 128 j = 2048 j (full row)

    __shared__ float tww[2][16][132];   // w2 plane, double buffered
    __shared__ float twm[2][16][132];   // mask-bias plane (0 or -30000)

    float ctv = __uint_as_float(*ctp);
    float c0  = fmaf(-DLOG2E, ctv, LLOG2E);   // -D*log2e*ct + log2(log2e)
    float es_i = es[(b * HH + w) * NN + i];

    const float* ed_p = ed + (size_t)(b * HH + w) * NN + q * 8;
    const __hip_bfloat16* ht_p = h_t + ((size_t)((b * HH + w) * HD + im)) * NN + q * 8;

    // staging map: 512 threads x 4 elements = 16 rows x 128 cols
    int srow = t >> 5;            // 0..15
    int scol = (t & 31) << 2;     // 0,4,...,124
    const int*   adj_s = adj + ((size_t)(b * NN + i0 + srow)) * NN + scol;
    const float* tm_s  = tm  + ((size_t)(b * NN + i0 + srow)) * NN + scol;

    float4v acc = {0.f, 0.f, 0.f, 0.f};
    float ls0 = 0.f, ls1 = 0.f;

    // prologue: stage round 0, prefetch round 1
    int4   pa = *(const int4*)(adj_s);
    float4 pt = *(const float4*)(tm_s);
    {
        float w0 = exp2f(fmaf(DLOG2E, pt.x, c0));
        float w1 = exp2f(fmaf(DLOG2E, pt.y, c0));
        float w2 = exp2f(fmaf(DLOG2E, pt.z, c0));
        float w3 = exp2f(fmaf(DLOG2E, pt.w, c0));
        *(float4*)&tww[0][srow][scol] = make_float4(w0, w1, w2, w3);
        *(float4*)&twm[0][srow][scol] = make_float4(
            (pa.x != 0) ? 0.f : MBIAS, (pa.y != 0) ? 0.f : MBIAS,
            (pa.z != 0) ? 0.f : MBIAS, (pa.w != 0) ? 0.f : MBIAS);
    }
    pa = *(const int4*)(adj_s + 128);
    pt = *(const float4*)(tm_s + 128);
    __syncthreads();

    for (int r = 0; r < R; r++) {
        int cur = r & 1;
        // stage round r+1 into the other buffer; prefetch round r+2
        if (r + 1 < R) {
            float w0 = exp2f(fmaf(DLOG2E, pt.x, c0));
            float w1 = exp2f(fmaf(DLOG2E, pt.y, c0));
            float w2 = exp2f(fmaf(DLOG2E, pt.z, c0));
            float w3 = exp2f(fmaf(DLOG2E, pt.w, c0));
            *(float4*)&tww[cur ^ 1][srow][scol] = make_float4(w0, w1, w2, w3);
            *(float4*)&twm[cur ^ 1][srow][scol] = make_float4(
                (pa.x != 0) ? 0.f : MBIAS, (pa.y != 0) ? 0.f : MBIAS,
                (pa.z != 0) ? 0.f : MBIAS, (pa.w != 0) ? 0.f : MBIAS);
            if (r + 2 < R) {
                pa = *(const int4*)(adj_s + (r + 2) * 128);
                pt = *(const float4*)(tm_s + (r + 2) * 128);
            }
        }
        // consume round r
        #pragma unroll
        for (int c4 = 0; c4 < 4; c4++) {
            int jl = c4 * 32 + q * 8;
            int jglob = r * 128 + c4 * 32;

            float4 w01 = *(const float4*)&tww[cur][im][jl];
            float4 w23 = *(const float4*)&tww[cur][im][jl + 4];
            float4 m01 = *(const float4*)&twm[cur][im][jl];
            float4 m23 = *(const float4*)&twm[cur][im][jl + 4];
            float4 e0 = *(const float4*)(ed_p + jglob);
            float4 e1 = *(const float4*)(ed_p + jglob + 4);
            uint4  hv = *(const uint4*)(ht_p + jglob);

            float wv[8] = {w01.x, w01.y, w01.z, w01.w, w23.x, w23.y, w23.z, w23.w};
            float mv[8] = {m01.x, m01.y, m01.z, m01.w, m23.x, m23.y, m23.z, m23.w};
            float ev[8] = {e0.x, e0.y, e0.z, e0.w, e1.x, e1.y, e1.z, e1.w};

            union { unsigned short us[8]; short8 v; } af;
            #pragma unroll
            for (int k = 0; k < 8; k++) {
                float s0 = es_i + ev[k];
                float sc = fmaxf(s0, ALPHA * s0);          // leaky_relu
                float pv = exp2f(fmaf(sc, wv[k], mv[k]));  // masked -> exp2(-3e4)=0
                if (k & 1) ls1 += pv; else ls0 += pv;
                __hip_bfloat16 hb = __float2bfloat16(pv);
                unsigned short ub;
                __builtin_memcpy(&ub, &hb, 2);
                af.us[k] = ub;
            }
            union { uint4 u; short8 v; } bf;
            bf.u = hv;
            acc = __builtin_amdgcn_mfma_f32_16x16x32_bf16(af.v, bf.v, acc, 0, 0, 0);
        }
        __syncthreads();
    }

    // row-sum l(i): lane (q,im) partial covers its j-slices; xor over q
    float lsum = ls0 + ls1;
    lsum += __shfl_xor(lsum, 16);
    lsum += __shfl_xor(lsum, 32);   // now lane (q,im) holds l(i0+im)

    // finalize: normalize + ELU + store. acc[r] is (row=q*4+r, col=im).
    #pragma unroll
    for (int r = 0; r < 4; r++) {
        int row = q * 4 + r;
        float lr = __shfl(lsum, (q << 4) | row);   // lane with im==row has l(row)
        float v = acc[r] / lr;
        v = (v > 0.f) ? v : expm1f(v);             // ELU
        out[((size_t)(b * NN + i0 + row)) * (HH * HD) + w * HD + im] = v;
    }
}

extern "C" void kernel_launch(void* const* d_in, const int* in_sizes, int n_in,
                              void* d_out, int out_size, void* d_ws, size_t ws_size,
                              hipStream_t stream) {
    const float* x   = (const float*)d_in[0];  // node_features fp32
    const int*   adj = (const int*)d_in[1];    // adjacency int32
    const float* tm  = (const float*)d_in[2];  // time_matrix fp32
    const float* W   = (const float*)d_in[3];  // W fp32
    const float* a   = (const float*)d_in[4];  // a fp32
    float* out = (float*)d_out;                // fp32 output

    float* wsf = (float*)d_ws;
    unsigned* ct = (unsigned*)wsf;                           // 1 word
    float* es = wsf + 64;                                    // 65,536
    float* ed = es + BN * HH * NN;                           // 65,536
    __hip_bfloat16* h_t = (__hip_bfloat16*)(ed + BN * HH * NN);  // 1,048,576 bf16
    // total ws use ~= 2.6 MB

    hipMemsetAsync(d_ws, 0, 4, stream);                      // ct = 0.0f (t >= 0)
    k_setup<<<1024 + 4096, 256, 0, stream>>>(x, W, a, tm, ct, h_t, es, ed);
    k_attn <<<BN * (NN / 16), 512, 0, stream>>>(adj, tm, h_t, es, ed, ct, out);
}